// Round 8
// baseline (1843.434 us; speedup 1.0000x reference)
//
#include <hip/hip_runtime.h>
#include <math.h>

#define BN_SC 0.9999950000374997f
#define BN2   0.9999900000999990f
#define LOGC  (-9.210340371976184f)

// ---- ws float offsets ----
#define OFF_S      0L         // 1280*200
#define OFF_BEFF2  257952L    // 64
#define OFF_C12    258016L    // 2
#define OFF_W2L    258304L    // 28672  [c][dt][o]
#define OFF_SPWT   286976L    // 204800 [vj][d]
#define OFF_WINT   491776L    // 12288  [c][i]
#define OFF_OWT    504064L    // 4096   [e][d]
#define OFF_F1T    508160L    // 8192   [c][r]
#define OFF_F2T    516352L    // 8192   [r][c]
#define OFF_FEATST 524544L    // 1024
#define OFF_XS0    525568L    // 81920
#define OFF_TN1O   607488L    // 4096
#define OFF_A      611584L    // 256000
#define OFF_PW     867584L    // 448
#define OFF_QW     868032L    // 448
#define OFF_B2G    868480L    // 64
#define OFF_CNT    868544L    // 200 ints
#define OFF_NBR    868800L    // 40000 ushort = 20000 floats
#define OFF_TV     1225984L   // 321600
#define OFF_Y      1547584L   // 4096000
#define OFF_G      1547584L   // 102400 -- reuses Y region (Y dead after ksp)
#define OFF_G2R    5643584L   // 16384000
#define OFF_M      5643584L   // 256000 -- reuses G2R region (dead after kconv2fb)

#define CHEB_N 64
struct ChebC { float c[CHEB_N]; float alpha, beta; };

__device__ inline float wsum(float v){ for(int o=32;o>0;o>>=1) v += __shfl_xor(v,o); return v; }
__device__ inline float wmax(float v){ for(int o=32;o>0;o>>=1) v = fmaxf(v,__shfl_xor(v,o)); return v; }

// ---------------- prep 1: spwT transpose + Weff2 + beff2 ----------------
__global__ void kprep1(const float* __restrict__ sp_w,
                       const float* __restrict__ fw2,
                       const float* __restrict__ w3, const float* __restrict__ w5, const float* __restrict__ w7,
                       const float* __restrict__ b3, const float* __restrict__ b5, const float* __restrict__ b7,
                       const float* __restrict__ fb2,
                       float* __restrict__ W)
{
    int bid = blockIdx.x, tid = threadIdx.x;
    if (bid < 64) {
        int d = bid;
        for (int vj = tid; vj < 3200; vj += 256)
            W[OFF_SPWT + (long)vj*64 + d] = sp_w[d*3200 + vj];
    } else {
        int o = bid - 64;
        for (int idx = tid; idx < 448; idx += 256) {
            int c = idx / 7, dt = idx % 7;
            float acc = 0.f;
            for (int cp = 0; cp < 64; cp++) {
                float f3 = fw2[o*192 + cp], f5 = fw2[o*192 + 64 + cp], f7 = fw2[o*192 + 128 + cp];
                if (dt >= 2 && dt <= 4) acc += f3 * w3[(cp*64 + c)*3 + (dt-2)];
                if (dt >= 1 && dt <= 5) acc += f5 * w5[(cp*64 + c)*5 + (dt-1)];
                acc += f7 * w7[(cp*64 + c)*7 + dt];
            }
            W[OFF_W2L + (long)(c*7+dt)*64 + o] = acc * BN2;
        }
        if (tid == 0) {
            float acc = fb2[o];
            for (int cp = 0; cp < 64; cp++)
                acc += (fw2[o*192+cp]*b3[cp] + fw2[o*192+64+cp]*b5[cp] + fw2[o*192+128+cp]*b7[cp]) * BN_SC;
            W[OFF_BEFF2 + o] = acc;
        }
    }
}

// ---------------- prep 2: c1/c2, PW/QW/B2G, neighbor lists (ballot compaction), transposes ----------------
__global__ void kprep2(const float* __restrict__ g1W, const float* __restrict__ g1a,
                       const float* __restrict__ w3, const float* __restrict__ w5, const float* __restrict__ w7,
                       const float* __restrict__ b3, const float* __restrict__ b5, const float* __restrict__ b7,
                       const float* __restrict__ fw1, const float* __restrict__ fb1,
                       const float* __restrict__ adj, const float* __restrict__ g2W,
                       const float* __restrict__ inw, const float* __restrict__ ow,
                       const float* __restrict__ f1, const float* __restrict__ f2,
                       float* __restrict__ W)
{
    __shared__ float weff[7168]; // [o][c][dt] 32*32*7
    __shared__ float p1l[224], q1l[224], be1l[32];
    int tid = threadIdx.x;
    int lane = tid & 63, wv = tid >> 6;
    if (tid == 0) {
        float c1 = 0.f, c2 = 0.f;
        for (int f = 0; f < 32; f++){ c1 += g1W[f]*g1a[f]; c2 += g1W[f]*g1a[32+f]; }
        W[OFF_C12] = c1; W[OFF_C12+1] = c2;
    }
    // neighbor lists via wave-parallel ballot compaction (coalesced adj reads)
    {
        int* cnti = (int*)(W + OFF_CNT);
        ushort* nbr = (ushort*)(W + OFF_NBR);
        for (int v = wv; v < 200; v += 4){
            int base = 0;
            #pragma unroll
            for (int u = 0; u < 4; u++){
                int j = u*64 + lane;
                bool pred = (j < 200) && (adj[v*200 + j] > 0.f);
                unsigned long long mask = __ballot(pred);
                int pos = __popcll(mask & ((1ULL << lane) - 1ULL));
                if (pred) nbr[v*200 + base + pos] = (ushort)j;
                base += __popcll(mask);
            }
            if (lane == 0) cnti[v] = base;
        }
    }
    for (int idx = tid; idx < 7168; idx += 256) {
        int o = idx/224, rem = idx%224, c = rem/7, dt = rem%7;
        float acc = 0.f;
        for (int cp = 0; cp < 32; cp++) {
            float f3 = fw1[o*96+cp], f5 = fw1[o*96+32+cp], f7 = fw1[o*96+64+cp];
            if (dt >= 2 && dt <= 4) acc += f3*w3[(cp*32+c)*3+(dt-2)];
            if (dt >= 1 && dt <= 5) acc += f5*w5[(cp*32+c)*5+(dt-1)];
            acc += f7*w7[(cp*32+c)*7+dt];
        }
        weff[idx] = acc * BN2;
    }
    __syncthreads();
    for (int idx = tid; idx < 224; idx += 256) {
        int o = idx/7, dt = idx%7;
        float p = 0.f, q = 0.f;
        for (int c = 0; c < 32; c++){
            float wv2 = weff[o*224 + c*7 + dt];
            float w0 = g1W[c];
            p += wv2 * fmaxf(w0, 0.f);
            q += wv2 * fmaxf(-w0, 0.f);
        }
        p1l[idx] = p; q1l[idx] = q;
    }
    if (tid < 32) {
        int o = tid;
        float acc = fb1[o];
        for (int cp = 0; cp < 32; cp++)
            acc += (fw1[o*96+cp]*b3[cp] + fw1[o*96+32+cp]*b5[cp] + fw1[o*96+64+cp]*b7[cp]) * BN_SC;
        be1l[o] = acc;
    }
    __syncthreads();
    for (int idx = tid; idx < 448; idx += 256){
        int f = idx/7, dt = idx%7;
        float ap = 0.f, aq = 0.f;
        for (int o = 0; o < 32; o++){
            float g = g2W[o*64+f];
            ap += g*p1l[o*7+dt]; aq += g*q1l[o*7+dt];
        }
        W[OFF_PW+idx] = ap; W[OFF_QW+idx] = aq;
    }
    if (tid < 64){
        float acc = 0.f;
        for (int o = 0; o < 32; o++) acc += g2W[o*64+tid]*be1l[o];
        W[OFF_B2G+tid] = acc;
    }
    for (int idx = tid; idx < 12288; idx += 256){ int i = idx%192; int c = idx/192; W[OFF_WINT+idx] = inw[i*64+c]; }
    for (int idx = tid; idx < 4096;  idx += 256){ int d = idx%64;  int e = idx/64;  W[OFF_OWT+idx]  = ow[d*64+e]; }
    for (int idx = tid; idx < 8192;  idx += 256){ int r = idx%128; int c = idx/128; W[OFF_F1T+idx]  = f1[r*64+c]; }
    for (int idx = tid; idx < 8192;  idx += 256){ int c = idx%64;  int r = idx/64;  W[OFF_F2T+idx]  = f2[c*128+r]; }
}

// ---------------- GAT1 via neighbor lists: s[bt][v] ----------------
__global__ void __launch_bounds__(256) kgat1(const float* __restrict__ x, float* __restrict__ W)
{
    __shared__ float xrow[200];
    int bt = blockIdx.x, tid = threadIdx.x;
    int lane = tid & 63, wv = tid >> 6;
    for (int i = tid; i < 200; i += 256) xrow[i] = x[bt*200+i];
    __syncthreads();
    float c1 = W[OFF_C12], c2 = W[OFF_C12+1];
    const int* cnti = (const int*)(W + OFF_CNT);
    const ushort* nbrl = (const ushort*)(W + OFF_NBR);
    for (int v = wv; v < 200; v += 4) {
        float xv = xrow[v];
        int cnt = cnti[v];
        float m = -3.4e38f, z[4], xj[4];
        #pragma unroll
        for (int u = 0; u < 4; u++){
            z[u] = -3.4e38f; xj[u] = 0.f;
            int k = u*64 + lane;
            if (u*64 < cnt && k < cnt){
                int j = nbrl[v*200 + k];
                xj[u] = xrow[j];
                float zz = c1*xv + c2*xj[u];
                z[u] = zz > 0.f ? zz : 0.2f*zz;
                m = fmaxf(m, z[u]);
            }
        }
        m = wmax(m);
        float den = 0.f, num = 0.f;
        #pragma unroll
        for (int u = 0; u < 4; u++){
            int k = u*64 + lane;
            if (u*64 < cnt && k < cnt){
                float p = __expf(z[u] - m);
                den += p; num += p * xj[u];
            }
        }
        #pragma unroll
        for (int o = 32; o > 0; o >>= 1){ den += __shfl_xor(den, o); num += __shfl_xor(num, o); }
        if (lane == 0) W[OFF_S + bt*200 + v] = num / den;
    }
}

// ---------------- GAT2 via neighbor lists: wh + softmax(sparse) + PV(sparse) ----------------
__global__ void __launch_bounds__(256) kgat2(const float* __restrict__ g2a, float* __restrict__ W)
{
    extern __shared__ float sm[];
    float* Xreg = sm;            // 3200: phase1 sp7(1400)+sn7(1400); phase3: per-wave (p,off) strips
    float* wh   = sm + 3200;     // 13000 [v][65] (padded stride)
    float* e1   = sm + 16200;    // 200
    float* e2   = sm + 16400;    // 200
    float* PWs  = sm + 16600;    // 448
    float* QWs  = sm + 17048;    // 448
    float* b2s  = sm + 17496;    // 64
    float* a2s  = sm + 17560;    // 128
    // total 17688 floats = 70752 B
    float* sp7 = Xreg; float* sn7 = Xreg + 1400;
    int bt = blockIdx.x, tid = threadIdx.x;
    int lane = tid & 63, wv = tid >> 6;
    for (int i = tid; i < 448; i += 256){ PWs[i] = W[OFF_PW+i]; QWs[i] = W[OFF_QW+i]; }
    if (tid < 64) b2s[tid] = W[OFF_B2G+tid];
    if (tid < 128) a2s[tid] = g2a[tid];
    {
        int b = bt / 80, t = bt % 80;
        for (int i = tid; i < 1400; i += 256){
            int dt = i/200, v = i%200, tp = t + dt - 3;
            float s = (tp >= 0 && tp < 80) ? W[OFF_S + (b*80+tp)*200 + v] : 0.f;
            sp7[i] = fmaxf(s, 0.f); sn7[i] = fmaxf(-s, 0.f);
        }
    }
    __syncthreads();
    // wh[v][f] (stride 65) = b2[f] + sum_dt PW[f,dt]*sp7[dt,v] + QW[f,dt]*sn7[dt,v]
    for (int i = tid; i < 12800; i += 256){
        int v = i >> 6, f = i & 63;
        float acc = b2s[f];
        #pragma unroll
        for (int dt = 0; dt < 7; dt++)
            acc += PWs[f*7+dt]*sp7[dt*200+v] + QWs[f*7+dt]*sn7[dt*200+v];
        wh[v*65+f] = acc;
    }
    __syncthreads();
    // e1,e2: one thread per node, serial 64-dot (stride-65 pad -> conflict-free)
    if (tid < 200){
        float a1 = 0.f, a2v = 0.f;
        #pragma unroll 8
        for (int f = 0; f < 64; f++){
            float w0 = wh[tid*65+f];
            a1 += w0*a2s[f]; a2v += w0*a2s[64+f];
        }
        e1[tid] = a1; e2[tid] = a2v;
    }
    __syncthreads();
    const int* cnti = (const int*)(W + OFF_CNT);
    const ushort* nbrl = (const ushort*)(W + OFF_NBR);
    float2* pnls = (float2*)(Xreg + wv*800);   // up to 200 (p, off) pairs per wave
    long outBase = OFF_G2R + (long)bt*200*64;
    int v0 = wv*50;
    for (int r = 0; r < 50; r++){
        int v = v0 + r;
        float ev = e1[v];
        int cnt = cnti[v];
        float m = -3.4e38f, z[4];
        int nb[4];
        #pragma unroll
        for (int u = 0; u < 4; u++){
            z[u] = -3.4e38f; nb[u] = 0;
            int k = u*64 + lane;
            if (u*64 < cnt && k < cnt){
                int j = nbrl[v*200 + k];
                nb[u] = j;
                float zz = ev + e2[j];
                z[u] = zz > 0.f ? zz : 0.2f*zz;
                m = fmaxf(m, z[u]);
            }
        }
        m = wmax(m);
        float den = 0.f;
        #pragma unroll
        for (int u = 0; u < 4; u++){
            int k = u*64 + lane;
            if (u*64 < cnt && k < cnt){
                float p = __expf(z[u] - m);
                den += p;
                pnls[k] = make_float2(p, __int_as_float(nb[u]*65));
            }
        }
        den = wsum(den);
        asm volatile("s_waitcnt lgkmcnt(0)" ::: "memory");
        float acc = 0.f;
        for (int k = 0; k < cnt; k++){
            float2 pn = pnls[k];
            acc += pn.x * wh[__float_as_int(pn.y) + lane];
        }
        W[outBase + (long)v*64 + lane] = fmaxf(acc, 0.f) * (1.f/den);
    }
}

// ---------------- conv2 (7-tap, 64ch) + fb(64->16,leaky 0.1) fused ----------------
__global__ void __launch_bounds__(256) kconv2fb(const float* __restrict__ fbw, const float* __restrict__ fbb,
                                                float* __restrict__ W)
{
    extern __shared__ float sm[];
    float* tile = sm;           // 11008 = 2*86*64
    float* fbws = sm + 11008;   // 16*65
    float* fbbs = sm + 12048;   // 16
    float* be2  = sm + 12064;   // 64
    int bid = blockIdx.x, tid = threadIdx.x;
    int b = bid/100, vp = bid%100, v0 = vp*2;
    int lane = tid & 63, wv = tid >> 6;
    for (int i = tid; i < 1024; i += 256) fbws[(i>>6)*65 + (i&63)] = fbw[i];
    if (tid < 16) fbbs[tid] = fbb[tid];
    if (tid < 64) be2[tid] = W[OFF_BEFF2+tid];
    for (int i = tid; i < 11008; i += 256){
        int vq = i/(86*64), tt = (i/64)%86, c = i%64, tp = tt-3;
        float val = 0.f;
        if (tp >= 0 && tp < 80) val = W[OFF_G2R + ((long)(b*80+tp)*200 + v0+vq)*64 + c];
        tile[i] = val;
    }
    __syncthreads();
    int vq = wv >> 1, t0 = (wv & 1)*40;
    float acc[40];
    #pragma unroll
    for (int k = 0; k < 40; k++) acc[k] = 0.f;
    for (int c = 0; c < 64; c++){
        float tvv[46];
        #pragma unroll
        for (int i = 0; i < 46; i++) tvv[i] = tile[(vq*86 + t0 + i)*64 + c];
        #pragma unroll
        for (int dt = 0; dt < 7; dt++){
            float wvv = W[OFF_W2L + (long)(c*7+dt)*64 + lane];
            #pragma unroll
            for (int k = 0; k < 40; k++) acc[k] += wvv * tvv[k+dt];
        }
    }
    __syncthreads();
    int row = wv*40;
    for (int k = 0; k < 40; k++) tile[(row+k)*64 + lane] = acc[k] + be2[lane];
    __syncthreads();
    for (int it = 0; it < 10; it++){
        int r = it*16 + (tid>>4), j = tid & 15;
        float a2 = fbbs[j];
        #pragma unroll 8
        for (int o = 0; o < 64; o++) a2 += fbws[j*65+o]*tile[r*64+o];
        a2 = a2 > 0.f ? a2 : 0.1f*a2;
        int vq2 = r/80, tt = r%80;
        W[OFF_Y + ((long)(b*80+tt)*200 + v0+vq2)*16 + j] = a2;
    }
}

// ---------------- sp linear 3200->64 ----------------
__global__ void __launch_bounds__(256) ksp(const float* __restrict__ sp_b, float* __restrict__ W)
{
    __shared__ float yb[3200];
    __shared__ float part[4][64];
    int bt = blockIdx.x, tid = threadIdx.x;
    int lane = tid & 63, wv = tid >> 6;
    for (int i = tid; i < 3200; i += 256) yb[i] = W[OFF_Y + (long)bt*3200 + i];
    __syncthreads();
    float acc = 0.f;
    int base = wv*800;
    for (int vj = 0; vj < 800; vj++)
        acc += W[OFF_SPWT + (long)(base+vj)*64 + lane] * yb[base+vj];
    part[wv][lane] = acc;
    __syncthreads();
    if (tid < 64){
        float s = part[0][tid]+part[1][tid]+part[2][tid]+part[3][tid] + sp_b[tid];
        W[OFF_XS0 + bt*64 + tid] = s;
    }
}

// ---------------- MHA + LN1 + FF + LN2 + mean(T) per batch ----------------
__global__ void __launch_bounds__(256) kattn(const float* __restrict__ inb, const float* __restrict__ ob,
    const float* __restrict__ l1g, const float* __restrict__ l1b,
    const float* __restrict__ l2g, const float* __restrict__ l2b,
    const float* __restrict__ f1b, const float* __restrict__ f2b,
    float* __restrict__ W)
{
    extern __shared__ float sm[];
    float* xb  = sm;          // 80*65
    float* qkv = sm + 5200;   // 80*193
    float* ao  = sm + 20640;  // 80*65
    float* pb  = sm + 25840;  // 4*80
    int b = blockIdx.x, tid = threadIdx.x, lane = tid & 63, wv = tid >> 6;
    for (int i = tid; i < 5120; i += 256){ int s = i>>6, c = i&63; xb[s*65+c] = W[OFF_XS0 + (b*80+s)*64 + c]; }
    __syncthreads();
    for (int s = wv; s < 80; s += 4){
        for (int ig = 0; ig < 3; ig++){
            int i = ig*64 + lane;
            float a = inb[i];
            #pragma unroll 8
            for (int c = 0; c < 64; c++) a += xb[s*65+c]*W[OFF_WINT + c*192 + i];
            qkv[s*193 + i] = a;
        }
    }
    __syncthreads();
    int h = wv;
    for (int i = 0; i < 80; i++){
        float qv[16];
        #pragma unroll
        for (int d = 0; d < 16; d++) qv[d] = qkv[i*193 + h*16 + d];
        float z[2];
        float m = -3.4e38f;
        #pragma unroll
        for (int u = 0; u < 2; u++){
            int jj = lane + u*64;
            z[u] = -3.4e38f;
            if (jj < 80){
                float a = 0.f;
                #pragma unroll
                for (int d = 0; d < 16; d++) a += qv[d]*qkv[jj*193 + 64 + h*16 + d];
                z[u] = a*0.25f;
                m = fmaxf(m, z[u]);
            }
        }
        m = wmax(m);
        float den = 0.f;
        #pragma unroll
        for (int u = 0; u < 2; u++){
            int jj = lane + u*64;
            if (jj < 80){
                float p = __expf(z[u]-m);
                pb[h*80+jj] = p;
                den += p;
            }
        }
        den = wsum(den);
        int d = lane & 15, jg = lane >> 4;
        float a = 0.f;
        for (int jo = 0; jo < 20; jo++){
            int jj = jg*20 + jo;
            a += pb[h*80+jj]*qkv[jj*193 + 128 + h*16 + d];
        }
        a += __shfl_xor(a, 16);
        a += __shfl_xor(a, 32);
        if (lane < 16) ao[i*65 + h*16 + lane] = a/den;
    }
    __syncthreads();
    for (int s = wv; s < 80; s += 4){
        float pr = ob[lane];
        #pragma unroll 8
        for (int e = 0; e < 64; e++) pr += ao[s*65+e]*W[OFF_OWT + e*64 + lane];
        float val = xb[s*65+lane] + pr;
        float mu = wsum(val)*(1.f/64.f);
        float dfv = val - mu;
        float var = wsum(dfv*dfv)*(1.f/64.f);
        xb[s*65+lane] = dfv*rsqrtf(var+1e-5f)*l1g[lane] + l1b[lane];
    }
    __syncthreads();
    for (int s = wv; s < 80; s += 4){
        for (int rg = 0; rg < 2; rg++){
            int r = rg*64+lane;
            float a = f1b[r];
            #pragma unroll 8
            for (int c = 0; c < 64; c++) a += xb[s*65+c]*W[OFF_F1T + c*128 + r];
            qkv[s*193 + r] = fmaxf(a, 0.f);
        }
    }
    __syncthreads();
    for (int s = wv; s < 80; s += 4){
        float a = f2b[lane];
        #pragma unroll 8
        for (int r = 0; r < 128; r++) a += qkv[s*193+r]*W[OFF_F2T + r*64 + lane];
        float val = xb[s*65+lane] + a;
        float mu = wsum(val)*(1.f/64.f);
        float dfv = val - mu;
        float var = wsum(dfv*dfv)*(1.f/64.f);
        xb[s*65+lane] = dfv*rsqrtf(var+1e-5f)*l2g[lane] + l2b[lane];
    }
    __syncthreads();
    if (tid < 64){
        float a = 0.f;
        for (int s = 0; s < 80; s++) a += xb[s*65+tid];
        W[OFF_FEATST + b*64 + tid] = a*(1.f/80.f);
    }
}

// ---------------- Gram: A = xc/sqrt(79), G = A A^T (5x5 register tiles, stride-204 LDS) ----------------
__global__ void __launch_bounds__(256) kgram(const float* __restrict__ x, float* __restrict__ W)
{
    extern __shared__ float sm[]; // xb[80*204] = 16320
    float* xb = sm;
    int b = blockIdx.x, tid = threadIdx.x;
    for (int i = tid; i < 16000; i += 256){ int t = i/200, n = i%200; xb[t*204+n] = x[b*16000 + i]; }
    __syncthreads();
    const float is79 = rsqrtf(79.f);
    if (tid < 200){
        int n = tid;
        float mu = 0.f;
        for (int t = 0; t < 80; t++) mu += xb[t*204+n];
        mu *= (1.f/80.f);
        for (int t = 0; t < 80; t++) xb[t*204+n] = (xb[t*204+n]-mu)*is79;
    }
    __syncthreads();
    for (int i = tid; i < 16000; i += 256){ int t = i/200, n = i%200; W[OFF_A + b*16000 + i] = xb[t*204+n]; }
    // G: 16x16 thread tiles of 5x5
    {
        int ti = (tid>>4)*5, tj = (tid&15)*5;
        const float4* X4 = (const float4*)xb;   // row stride 51 float4
        float acc[25];
        #pragma unroll
        for (int i = 0; i < 25; i++) acc[i] = 0.f;
        for (int n4 = 0; n4 < 50; n4++){
            float4 xi[5], xj[5];
            #pragma unroll
            for (int r = 0; r < 5; r++) xi[r] = X4[(ti+r)*51 + n4];
            #pragma unroll
            for (int c = 0; c < 5; c++) xj[c] = X4[(tj+c)*51 + n4];
            #pragma unroll
            for (int r = 0; r < 5; r++)
                #pragma unroll
                for (int c = 0; c < 5; c++)
                    acc[r*5+c] += xi[r].x*xj[c].x + xi[r].y*xj[c].y + xi[r].z*xj[c].z + xi[r].w*xj[c].w;
        }
        #pragma unroll
        for (int r = 0; r < 5; r++)
            #pragma unroll
            for (int c = 0; c < 5; c++)
                W[OFF_G + b*6400 + (ti+r)*80 + (tj+c)] = acc[r*5+c];
    }
}

// ---------------- Chebyshev: M = f(G)·A, 16-col chunks, 208 blocks, 3 LDS ops/j ----------------
__global__ void __launch_bounds__(256) kcheb(ChebC C, float* __restrict__ W)
{
    extern __shared__ float sm[];
    float* Gs = sm;          // 10240
    float* Tb = sm + 10240;  // 2x1280
    int blk = blockIdx.x, tid = threadIdx.x;
    int b = blk / 13, ch = blk % 13;
    int cl = tid & 15, rg = tid >> 4;
    int c = ch*16 + cl;
    bool act = (c < 200);
    for (int idx = tid; idx < 6400; idx += 256){
        int jj = idx / 80, ii = idx % 80;
        float v = W[OFF_G + b*6400 + jj*80 + ii] * C.alpha + ((ii==jj)? C.beta : 0.f);
        Gs[jj*128 + (ii/5)*8 + (ii%5)] = v;
    }
    const float* Ab = &W[OFF_A + (long)b*16000];
    float Tprev[5], Tcur[5], Macc[5];
    float* B0 = Tb; float* B1 = Tb + 1280;
    if (act){
        #pragma unroll
        for (int r = 0; r < 5; r++){
            int i = rg*5 + r;
            float v = Ab[i*200 + c];
            B0[i*16 + cl] = v;
            Tprev[r] = v;
            Macc[r] = C.c[0]*v;
        }
    }
    __syncthreads();
    const float* grow = Gs + rg*8;
    {
        float t[5] = {0.f,0.f,0.f,0.f,0.f};
        if (act){
            for (int j = 0; j < 80; j++){
                float bv = B0[j*16 + cl];
                const float4 g4 = *(const float4*)(grow + j*128);
                float g1 = grow[j*128 + 4];
                t[0] += g4.x*bv; t[1] += g4.y*bv; t[2] += g4.z*bv; t[3] += g4.w*bv; t[4] += g1*bv;
            }
            #pragma unroll
            for (int r = 0; r < 5; r++){
                Tcur[r] = t[r];
                Macc[r] += C.c[1]*t[r];
                B1[(rg*5+r)*16 + cl] = t[r];
            }
        }
        __syncthreads();
    }
    for (int k = 2; k < CHEB_N; k++){
        const float* Rb = Tb + ((k-1)&1)*1280;
        float* Wb = Tb + (k&1)*1280;
        if (act){
            float t[5] = {0.f,0.f,0.f,0.f,0.f};
            for (int j = 0; j < 80; j++){
                float bv = Rb[j*16 + cl];
                const float4 g4 = *(const float4*)(grow + j*128);
                float g1 = grow[j*128 + 4];
                t[0] += g4.x*bv; t[1] += g4.y*bv; t[2] += g4.z*bv; t[3] += g4.w*bv; t[4] += g1*bv;
            }
            float ck = C.c[k];
            #pragma unroll
            for (int r = 0; r < 5; r++){
                float tn = 2.f*t[r] - Tprev[r];
                Macc[r] += ck*tn;
                Tprev[r] = Tcur[r];
                Tcur[r] = tn;
                Wb[(rg*5+r)*16 + cl] = tn;
            }
        }
        __syncthreads();
    }
    if (act){
        #pragma unroll
        for (int r = 0; r < 5; r++)
            W[OFF_M + (long)b*16000 + (rg*5+r)*200 + c] = Macc[r];
    }
}

// ---------------- tv = upper-tri(A^T M + logc*I) ----------------
__global__ void ktv(float* __restrict__ W)
{
    __shared__ float an[80];
    int bid = blockIdx.x, tid = threadIdx.x;
    int b = bid/200, n = bid%200;
    for (int i = tid; i < 80; i += 64) an[i] = W[OFF_A + (long)b*16000 + i*200 + n];
    __syncthreads();
    long tb = OFF_TV + (long)b*20100 + (long)n*200 - (long)n*(n-1)/2;
    for (int m = n + tid; m < 200; m += 64){
        float a = 0.f;
        for (int i = 0; i < 80; i++) a += an[i]*W[OFF_M + (long)b*16000 + i*200 + m];
        if (m == n) a += LOGC;
        W[tb + (m-n)] = a;
    }
}

// ---------------- tn1 linear 20100->256 (block per output r, all batches) ----------------
__global__ void __launch_bounds__(256) ktn1(const float* __restrict__ w, const float* __restrict__ bias,
                                            float* __restrict__ W)
{
    __shared__ float part[4][16];
    int r = blockIdx.x, tid = threadIdx.x, lane = tid & 63, wv = tid >> 6;
    float acc[16];
    #pragma unroll
    for (int i = 0; i < 16; i++) acc[i] = 0.f;
    for (int vj = tid; vj < 20100; vj += 256){
        float wvv = w[(long)r*20100 + vj];
        #pragma unroll
        for (int bb = 0; bb < 16; bb++) acc[bb] += wvv * W[OFF_TV + (long)bb*20100 + vj];
    }
    #pragma unroll
    for (int bb = 0; bb < 16; bb++) acc[bb] = wsum(acc[bb]);
    if (lane == 0){
        #pragma unroll
        for (int bb = 0; bb < 16; bb++) part[wv][bb] = acc[bb];
    }
    __syncthreads();
    if (tid < 16){
        float s = part[0][tid]+part[1][tid]+part[2][tid]+part[3][tid] + bias[r];
        W[OFF_TN1O + tid*256 + r] = s;
    }
}

// ---------------- head: tn2 + concat + cls/site (one block per batch) ----------------
__global__ void __launch_bounds__(256) khead(const float* __restrict__ tn2w, const float* __restrict__ tn2b,
                      const float* __restrict__ cl1w, const float* __restrict__ cl1b,
                      const float* __restrict__ cl2w, const float* __restrict__ cl2b,
                      const float* __restrict__ sc1w, const float* __restrict__ sc1b,
                      const float* __restrict__ sc2w, const float* __restrict__ sc2b,
                      const float* __restrict__ W, float* __restrict__ out)
{
    __shared__ float g[256], feats[128], h1[64], h2[32];
    int b = blockIdx.x, tid = threadIdx.x;
    float v = W[OFF_TN1O + b*256 + tid] * BN_SC;
    g[tid] = v > 0.f ? v : 0.1f*v;
    if (tid < 64) feats[tid] = W[OFF_FEATST + b*64 + tid];
    __syncthreads();
    {
        int o = tid >> 2, s3 = tid & 3;
        const float* wrow = tn2w + o*256 + s3*64;
        const float* grow = g + s3*64;
        float acc = 0.f;
        #pragma unroll 8
        for (int e = 0; e < 64; e++) acc += wrow[e]*grow[e];
        acc += __shfl_xor(acc, 1);
        acc += __shfl_xor(acc, 2);
        if (s3 == 0) feats[64+o] = fmaxf(acc + tn2b[o], 0.f);
    }
    __syncthreads();
    if (tid < 64){
        float a = cl1b[tid];
        #pragma unroll 8
        for (int k = 0; k < 128; k++) a += cl1w[tid*128+k]*feats[k];
        h1[tid] = fmaxf(a, 0.f);
    } else if (tid < 96){
        int i = tid-64;
        float a = sc1b[i];
        #pragma unroll 8
        for (int k = 0; k < 128; k++) a += sc1w[i*128+k]*feats[k];
        h2[i] = fmaxf(a, 0.f);
    }
    __syncthreads();
    if (tid < 2){
        float a = cl2b[tid];
        for (int i = 0; i < 64; i++) a += cl2w[tid*64+i]*h1[i];
        out[b*2+tid] = a;
    } else if (tid >= 32 && tid < 49){
        int o = tid-32;
        float a = sc2b[o];
        for (int i = 0; i < 32; i++) a += sc2w[o*32+i]*h2[i];
        out[32 + b*17 + o] = a;
    }
}

extern "C" void kernel_launch(void* const* d_in, const int* in_sizes, int n_in,
                              void* d_out, int out_size, void* d_ws, size_t ws_size,
                              hipStream_t stream)
{
    const float* x     = (const float*)d_in[0];
    const float* adj   = (const float*)d_in[1];
    const float* g1W   = (const float*)d_in[2];
    const float* g1a   = (const float*)d_in[3];
    const float* b1c3w = (const float*)d_in[4];
    const float* b1c3b = (const float*)d_in[5];
    const float* b1c5w = (const float*)d_in[6];
    const float* b1c5b = (const float*)d_in[7];
    const float* b1c7w = (const float*)d_in[8];
    const float* b1c7b = (const float*)d_in[9];
    const float* b1fw  = (const float*)d_in[10];
    const float* b1fb  = (const float*)d_in[11];
    const float* g2W   = (const float*)d_in[12];
    const float* g2a   = (const float*)d_in[13];
    const float* b2c3w = (const float*)d_in[14];
    const float* b2c3b = (const float*)d_in[15];
    const float* b2c5w = (const float*)d_in[16];
    const float* b2c5b = (const float*)d_in[17];
    const float* b2c7w = (const float*)d_in[18];
    const float* b2c7b = (const float*)d_in[19];
    const float* b2fw  = (const float*)d_in[20];
    const float* b2fb  = (const float*)d_in[21];
    const float* fbw   = (const float*)d_in[22];
    const float* fbb   = (const float*)d_in[23];
    const float* spw   = (const float*)d_in[24];
    const float* spb   = (const float*)d_in[25];
    const float* ainw  = (const float*)d_in[26];
    const float* ainb  = (const float*)d_in[27];
    const float* aow   = (const float*)d_in[28];
    const float* aob   = (const float*)d_in[29];
    const float* ln1g  = (const float*)d_in[30];
    const float* ln1b  = (const float*)d_in[31];
    const float* ln2g  = (const float*)d_in[32];
    const float* ln2b  = (const float*)d_in[33];
    const float* ff1w  = (const float*)d_in[34];
    const float* ff1b  = (const float*)d_in[35];
    const float* ff2w  = (const float*)d_in[36];
    const float* ff2b  = (const float*)d_in[37];
    const float* tn1w  = (const float*)d_in[38];
    const float* tn1b  = (const float*)d_in[39];
    const float* tn2w  = (const float*)d_in[40];
    const float* tn2b  = (const float*)d_in[41];
    const float* cl1w  = (const float*)d_in[42];
    const float* cl1b  = (const float*)d_in[43];
    const float* cl2w  = (const float*)d_in[44];
    const float* cl2b  = (const float*)d_in[45];
    const float* sc1w  = (const float*)d_in[46];
    const float* sc1b  = (const float*)d_in[47];
    const float* sc2w  = (const float*)d_in[48];
    const float* sc2b  = (const float*)d_in[49];
    float* W = (float*)d_ws;
    float* out = (float*)d_out;

    // Chebyshev coefficients of f(x)=log1p(x*1e4)/x on [0.10, 9.0] (host, deterministic)
    ChebC ch;
    {
        const double aa = 0.10, bb = 9.0;
        const int NK = 128;
        const double PI = 3.14159265358979323846;
        for (int k = 0; k < CHEB_N; k++){
            double s = 0.0;
            for (int j = 0; j < NK; j++){
                double th = PI*(j+0.5)/NK;
                double xx = 0.5*(bb+aa) + 0.5*(bb-aa)*cos(th);
                double f = log1p(xx*1e4)/xx;
                s += f*cos(k*th);
            }
            double ck = 2.0*s/NK;
            ch.c[k] = (float)(k==0 ? 0.5*ck : ck);
        }
        ch.alpha = (float)(2.0/(bb-aa));
        ch.beta  = (float)(-(bb+aa)/(bb-aa));
    }

    kprep1<<<128, 256, 0, stream>>>(spw, b2fw, b2c3w, b2c5w, b2c7w, b2c3b, b2c5b, b2c7b, b2fb, W);
    kprep2<<<1, 256, 0, stream>>>(g1W, g1a, b1c3w, b1c5w, b1c7w, b1c3b, b1c5b, b1c7b, b1fw, b1fb,
                                  adj, g2W, ainw, aow, ff1w, ff2w, W);
    kgat1<<<1280, 256, 0, stream>>>(x, W);
    kgat2<<<1280, 256, 70752, stream>>>(g2a, W);
    kconv2fb<<<1600, 256, 48512, stream>>>(fbw, fbb, W);
    ksp<<<1280, 256, 0, stream>>>(spb, W);
    kattn<<<16, 256, 104640, stream>>>(ainb, aob, ln1g, ln1b, ln2g, ln2b, ff1b, ff2b, W);
    kgram<<<16, 256, 65280, stream>>>(x, W);
    kcheb<<<208, 256, 51200, stream>>>(ch, W);
    ktv<<<3200, 64, 0, stream>>>(W);
    ktn1<<<256, 256, 0, stream>>>(tn1w, tn1b, W);
    khead<<<16, 256, 0, stream>>>(tn2w, tn2b, cl1w, cl1b, cl2w, cl2b, sc1w, sc1b, sc2w, sc2b, W, out);
}

// Round 9
// 1367.136 us; speedup vs baseline: 1.3484x; 1.3484x over previous
//
#include <hip/hip_runtime.h>
#include <math.h>

#define BN_SC 0.9999950000374997f
#define BN2   0.9999900000999990f
#define LOGC  (-9.210340371976184f)

// ---- ws float offsets ----
#define OFF_S      0L         // 1280*200
#define OFF_BEFF2  257952L    // 64
#define OFF_C12    258016L    // 2
#define OFF_W2L    258304L    // 28672  [c][dt][o]
#define OFF_SPWT   286976L    // 204800 [vj][d]
#define OFF_WINT   491776L    // 12288  [c][i]
#define OFF_OWT    504064L    // 4096   [e][d]
#define OFF_F1T    508160L    // 8192   [c][r]
#define OFF_F2T    516352L    // 8192   [r][c]
#define OFF_FEATST 524544L    // 1024
#define OFF_XS0    525568L    // 81920
#define OFF_TN1O   607488L    // 4096
#define OFF_A      611584L    // 256000
#define OFF_PW     867584L    // 448
#define OFF_QW     868032L    // 448
#define OFF_B2G    868480L    // 64
#define OFF_CNT    868544L    // 200 ints
#define OFF_NBR    868800L    // 40000 ushort = 20000 floats
#define OFF_TV     1225984L   // 321600
#define OFF_Y      1547584L   // 4096000
#define OFF_G      1547584L   // 102400 -- reuses Y region (Y dead after ksp)
#define OFF_G2R    5643584L   // 16384000
#define OFF_M      5643584L   // 256000 -- reuses G2R region (dead after kconv2fb)

#define CHEB_N 64
struct ChebC { float c[CHEB_N]; float alpha, beta; };

__device__ inline float wsum(float v){ for(int o=32;o>0;o>>=1) v += __shfl_xor(v,o); return v; }
__device__ inline float wmax(float v){ for(int o=32;o>0;o>>=1) v = fmaxf(v,__shfl_xor(v,o)); return v; }

// ---------------- merged prep: 163 blocks of independent roles ----------------
// bid 0-63   : SPWT transpose (per output column d)
// bid 64-127 : W2L effective conv2 weights (per output channel o)
// bid 128-152: neighbor lists, 8 rows per block (ballot compaction)
// bid 153    : c1/c2 + v-contraction PW/QW/B2G chain (weff eliminated algebraically)
// bid 154-157: WINT transpose (3072 each)
// bid 158    : OWT transpose
// bid 159-160: F1T transpose (4096 each)
// bid 161-162: F2T transpose (4096 each)
__global__ void __launch_bounds__(256) kprep(
    const float* __restrict__ sp_w,
    const float* __restrict__ fw2,
    const float* __restrict__ w3b, const float* __restrict__ w5b, const float* __restrict__ w7b,
    const float* __restrict__ b3b, const float* __restrict__ b5b, const float* __restrict__ b7b,
    const float* __restrict__ fb2,
    const float* __restrict__ g1W, const float* __restrict__ g1a,
    const float* __restrict__ w3a, const float* __restrict__ w5a, const float* __restrict__ w7a,
    const float* __restrict__ b3a, const float* __restrict__ b5a, const float* __restrict__ b7a,
    const float* __restrict__ fw1, const float* __restrict__ fb1,
    const float* __restrict__ adj, const float* __restrict__ g2W,
    const float* __restrict__ inw, const float* __restrict__ ow,
    const float* __restrict__ f1, const float* __restrict__ f2,
    float* __restrict__ W)
{
    __shared__ float rp[32], rq[32];
    __shared__ float v3p[32][3], v3q[32][3], v5p[32][5], v5q[32][5], v7p[32][7], v7q[32][7];
    __shared__ float p1l[224], q1l[224], be1l[32];
    int bid = blockIdx.x, tid = threadIdx.x;
    int lane = tid & 63, wv = tid >> 6;
    if (bid < 64) {
        int d = bid;
        for (int vj = tid; vj < 3200; vj += 256)
            W[OFF_SPWT + (long)vj*64 + d] = sp_w[d*3200 + vj];
    } else if (bid < 128) {
        int o = bid - 64;
        for (int idx = tid; idx < 448; idx += 256) {
            int c = idx / 7, dt = idx % 7;
            float acc = 0.f;
            for (int cp = 0; cp < 64; cp++) {
                float f3 = fw2[o*192 + cp], f5 = fw2[o*192 + 64 + cp], f7 = fw2[o*192 + 128 + cp];
                if (dt >= 2 && dt <= 4) acc += f3 * w3b[(cp*64 + c)*3 + (dt-2)];
                if (dt >= 1 && dt <= 5) acc += f5 * w5b[(cp*64 + c)*5 + (dt-1)];
                acc += f7 * w7b[(cp*64 + c)*7 + dt];
            }
            W[OFF_W2L + (long)(c*7+dt)*64 + o] = acc * BN2;
        }
        if (tid == 0) {
            float acc = fb2[o];
            for (int cp = 0; cp < 64; cp++)
                acc += (fw2[o*192+cp]*b3b[cp] + fw2[o*192+64+cp]*b5b[cp] + fw2[o*192+128+cp]*b7b[cp]) * BN_SC;
            W[OFF_BEFF2 + o] = acc;
        }
    } else if (bid < 153) {
        // neighbor lists: 8 rows per block
        int base_v = (bid - 128)*8;
        int* cnti = (int*)(W + OFF_CNT);
        ushort* nbr = (ushort*)(W + OFF_NBR);
        for (int r = wv; r < 8; r += 4){
            int v = base_v + r;
            if (v < 200){
                int base = 0;
                #pragma unroll
                for (int u = 0; u < 4; u++){
                    int j = u*64 + lane;
                    bool pred = (j < 200) && (adj[v*200 + j] > 0.f);
                    unsigned long long mask = __ballot(pred);
                    int pos = __popcll(mask & ((1ULL << lane) - 1ULL));
                    if (pred) nbr[v*200 + base + pos] = (ushort)j;
                    base += __popcll(mask);
                }
                if (lane == 0) cnti[v] = base;
            }
        }
    } else if (bid == 153) {
        // PW/QW/B2G chain with weff eliminated: contract over c first
        if (tid < 32){ float w0 = g1W[tid]; rp[tid] = fmaxf(w0, 0.f); rq[tid] = fmaxf(-w0, 0.f); }
        if (tid == 64) {
            float c1 = 0.f, c2 = 0.f;
            for (int f = 0; f < 32; f++){ c1 += g1W[f]*g1a[f]; c2 += g1W[f]*g1a[32+f]; }
            W[OFF_C12] = c1; W[OFF_C12+1] = c2;
        }
        __syncthreads();
        // v{3,5,7}{p,q}[cp][k] = sum_c relu(+-g1W[c]) * w{3,5,7}a[cp][c][k]
        for (int idx = tid; idx < 480; idx += 256){
            int cp = idx / 15, kk = idx % 15;
            float ap = 0.f, aq = 0.f;
            if (kk < 3){
                for (int c = 0; c < 32; c++){ float wv2 = w3a[(cp*32+c)*3 + kk]; ap += rp[c]*wv2; aq += rq[c]*wv2; }
                v3p[cp][kk] = ap; v3q[cp][kk] = aq;
            } else if (kk < 8){
                int k = kk - 3;
                for (int c = 0; c < 32; c++){ float wv2 = w5a[(cp*32+c)*5 + k]; ap += rp[c]*wv2; aq += rq[c]*wv2; }
                v5p[cp][k] = ap; v5q[cp][k] = aq;
            } else {
                int k = kk - 8;
                for (int c = 0; c < 32; c++){ float wv2 = w7a[(cp*32+c)*7 + k]; ap += rp[c]*wv2; aq += rq[c]*wv2; }
                v7p[cp][k] = ap; v7q[cp][k] = aq;
            }
        }
        __syncthreads();
        for (int idx = tid; idx < 224; idx += 256){
            int o = idx/7, dt = idx%7;
            float ap = 0.f, aq = 0.f;
            for (int cp = 0; cp < 32; cp++){
                float f3 = fw1[o*96+cp], f5 = fw1[o*96+32+cp], f7 = fw1[o*96+64+cp];
                if (dt >= 2 && dt <= 4){ ap += f3*v3p[cp][dt-2]; aq += f3*v3q[cp][dt-2]; }
                if (dt >= 1 && dt <= 5){ ap += f5*v5p[cp][dt-1]; aq += f5*v5q[cp][dt-1]; }
                ap += f7*v7p[cp][dt]; aq += f7*v7q[cp][dt];
            }
            p1l[idx] = ap * BN2; q1l[idx] = aq * BN2;
        }
        if (tid < 32) {
            int o = tid;
            float acc = fb1[o];
            for (int cp = 0; cp < 32; cp++)
                acc += (fw1[o*96+cp]*b3a[cp] + fw1[o*96+32+cp]*b5a[cp] + fw1[o*96+64+cp]*b7a[cp]) * BN_SC;
            be1l[o] = acc;
        }
        __syncthreads();
        for (int idx = tid; idx < 448; idx += 256){
            int f = idx/7, dt = idx%7;
            float ap = 0.f, aq = 0.f;
            for (int o = 0; o < 32; o++){
                float g = g2W[o*64+f];
                ap += g*p1l[o*7+dt]; aq += g*q1l[o*7+dt];
            }
            W[OFF_PW+idx] = ap; W[OFF_QW+idx] = aq;
        }
        if (tid < 64){
            float acc = 0.f;
            for (int o = 0; o < 32; o++) acc += g2W[o*64+tid]*be1l[o];
            W[OFF_B2G+tid] = acc;
        }
    } else if (bid < 158) {
        int ofs = (bid - 154)*3072;
        for (int k = tid; k < 3072; k += 256){
            int idx = ofs + k;
            int i = idx%192, c = idx/192;
            W[OFF_WINT+idx] = inw[i*64+c];
        }
    } else if (bid == 158) {
        for (int idx = tid; idx < 4096; idx += 256){
            int d = idx%64, e = idx/64;
            W[OFF_OWT+idx] = ow[d*64+e];
        }
    } else if (bid < 161) {
        int ofs = (bid - 159)*4096;
        for (int k = tid; k < 4096; k += 256){
            int idx = ofs + k;
            int r = idx%128, c = idx/128;
            W[OFF_F1T+idx] = f1[r*64+c];
        }
    } else {
        int ofs = (bid - 161)*4096;
        for (int k = tid; k < 4096; k += 256){
            int idx = ofs + k;
            int c = idx%64, r = idx/64;
            W[OFF_F2T+idx] = f2[c*128+r];
        }
    }
}

// ---------------- GAT1 via neighbor lists: s[bt][v] ----------------
__global__ void __launch_bounds__(256) kgat1(const float* __restrict__ x, float* __restrict__ W)
{
    __shared__ float xrow[200];
    int bt = blockIdx.x, tid = threadIdx.x;
    int lane = tid & 63, wv = tid >> 6;
    for (int i = tid; i < 200; i += 256) xrow[i] = x[bt*200+i];
    __syncthreads();
    float c1 = W[OFF_C12], c2 = W[OFF_C12+1];
    const int* cnti = (const int*)(W + OFF_CNT);
    const ushort* nbrl = (const ushort*)(W + OFF_NBR);
    for (int v = wv; v < 200; v += 4) {
        float xv = xrow[v];
        int cnt = cnti[v];
        float m = -3.4e38f, z[4], xj[4];
        #pragma unroll
        for (int u = 0; u < 4; u++){
            z[u] = -3.4e38f; xj[u] = 0.f;
            int k = u*64 + lane;
            if (u*64 < cnt && k < cnt){
                int j = nbrl[v*200 + k];
                xj[u] = xrow[j];
                float zz = c1*xv + c2*xj[u];
                z[u] = zz > 0.f ? zz : 0.2f*zz;
                m = fmaxf(m, z[u]);
            }
        }
        m = wmax(m);
        float den = 0.f, num = 0.f;
        #pragma unroll
        for (int u = 0; u < 4; u++){
            int k = u*64 + lane;
            if (u*64 < cnt && k < cnt){
                float p = __expf(z[u] - m);
                den += p; num += p * xj[u];
            }
        }
        #pragma unroll
        for (int o = 32; o > 0; o >>= 1){ den += __shfl_xor(den, o); num += __shfl_xor(num, o); }
        if (lane == 0) W[OFF_S + bt*200 + v] = num / den;
    }
}

// ---------------- GAT2 via neighbor lists: wh + softmax(sparse) + PV(sparse) ----------------
__global__ void __launch_bounds__(256) kgat2(const float* __restrict__ g2a, float* __restrict__ W)
{
    extern __shared__ float sm[];
    float* Xreg = sm;            // 3200: phase1 sp7(1400)+sn7(1400); phase3: per-wave (p,off) strips
    float* wh   = sm + 3200;     // 13000 [v][65] (padded stride)
    float* e1   = sm + 16200;    // 200
    float* e2   = sm + 16400;    // 200
    float* PWs  = sm + 16600;    // 448
    float* QWs  = sm + 17048;    // 448
    float* b2s  = sm + 17496;    // 64
    float* a2s  = sm + 17560;    // 128
    // total 17688 floats = 70752 B
    float* sp7 = Xreg; float* sn7 = Xreg + 1400;
    int bt = blockIdx.x, tid = threadIdx.x;
    int lane = tid & 63, wv = tid >> 6;
    for (int i = tid; i < 448; i += 256){ PWs[i] = W[OFF_PW+i]; QWs[i] = W[OFF_QW+i]; }
    if (tid < 64) b2s[tid] = W[OFF_B2G+tid];
    if (tid < 128) a2s[tid] = g2a[tid];
    {
        int b = bt / 80, t = bt % 80;
        for (int i = tid; i < 1400; i += 256){
            int dt = i/200, v = i%200, tp = t + dt - 3;
            float s = (tp >= 0 && tp < 80) ? W[OFF_S + (b*80+tp)*200 + v] : 0.f;
            sp7[i] = fmaxf(s, 0.f); sn7[i] = fmaxf(-s, 0.f);
        }
    }
    __syncthreads();
    // wh[v][f] (stride 65) = b2[f] + sum_dt PW[f,dt]*sp7[dt,v] + QW[f,dt]*sn7[dt,v]
    for (int i = tid; i < 12800; i += 256){
        int v = i >> 6, f = i & 63;
        float acc = b2s[f];
        #pragma unroll
        for (int dt = 0; dt < 7; dt++)
            acc += PWs[f*7+dt]*sp7[dt*200+v] + QWs[f*7+dt]*sn7[dt*200+v];
        wh[v*65+f] = acc;
    }
    __syncthreads();
    // e1,e2: one thread per node, serial 64-dot (stride-65 pad -> conflict-free)
    if (tid < 200){
        float a1 = 0.f, a2v = 0.f;
        #pragma unroll 8
        for (int f = 0; f < 64; f++){
            float w0 = wh[tid*65+f];
            a1 += w0*a2s[f]; a2v += w0*a2s[64+f];
        }
        e1[tid] = a1; e2[tid] = a2v;
    }
    __syncthreads();
    const int* cnti = (const int*)(W + OFF_CNT);
    const ushort* nbrl = (const ushort*)(W + OFF_NBR);
    float2* pnls = (float2*)(Xreg + wv*800);   // up to 200 (p, off) pairs per wave
    long outBase = OFF_G2R + (long)bt*200*64;
    int v0 = wv*50;
    for (int r = 0; r < 50; r++){
        int v = v0 + r;
        float ev = e1[v];
        int cnt = cnti[v];
        float m = -3.4e38f, z[4];
        int nb[4];
        #pragma unroll
        for (int u = 0; u < 4; u++){
            z[u] = -3.4e38f; nb[u] = 0;
            int k = u*64 + lane;
            if (u*64 < cnt && k < cnt){
                int j = nbrl[v*200 + k];
                nb[u] = j;
                float zz = ev + e2[j];
                z[u] = zz > 0.f ? zz : 0.2f*zz;
                m = fmaxf(m, z[u]);
            }
        }
        m = wmax(m);
        float den = 0.f;
        #pragma unroll
        for (int u = 0; u < 4; u++){
            int k = u*64 + lane;
            if (u*64 < cnt && k < cnt){
                float p = __expf(z[u] - m);
                den += p;
                pnls[k] = make_float2(p, __int_as_float(nb[u]*65));
            }
        }
        den = wsum(den);
        asm volatile("s_waitcnt lgkmcnt(0)" ::: "memory");
        float acc = 0.f;
        for (int k = 0; k < cnt; k++){
            float2 pn = pnls[k];
            acc += pn.x * wh[__float_as_int(pn.y) + lane];
        }
        W[outBase + (long)v*64 + lane] = fmaxf(acc, 0.f) * (1.f/den);
    }
}

// ---------------- conv2 (7-tap, 64ch) + fb(64->16,leaky 0.1) fused ----------------
__global__ void __launch_bounds__(256) kconv2fb(const float* __restrict__ fbw, const float* __restrict__ fbb,
                                                float* __restrict__ W)
{
    extern __shared__ float sm[];
    float* tile = sm;           // 11008 = 2*86*64
    float* fbws = sm + 11008;   // 16*65
    float* fbbs = sm + 12048;   // 16
    float* be2  = sm + 12064;   // 64
    int bid = blockIdx.x, tid = threadIdx.x;
    int b = bid/100, vp = bid%100, v0 = vp*2;
    int lane = tid & 63, wv = tid >> 6;
    for (int i = tid; i < 1024; i += 256) fbws[(i>>6)*65 + (i&63)] = fbw[i];
    if (tid < 16) fbbs[tid] = fbb[tid];
    if (tid < 64) be2[tid] = W[OFF_BEFF2+tid];
    for (int i = tid; i < 11008; i += 256){
        int vq = i/(86*64), tt = (i/64)%86, c = i%64, tp = tt-3;
        float val = 0.f;
        if (tp >= 0 && tp < 80) val = W[OFF_G2R + ((long)(b*80+tp)*200 + v0+vq)*64 + c];
        tile[i] = val;
    }
    __syncthreads();
    int vq = wv >> 1, t0 = (wv & 1)*40;
    float acc[40];
    #pragma unroll
    for (int k = 0; k < 40; k++) acc[k] = 0.f;
    for (int c = 0; c < 64; c++){
        float tvv[46];
        #pragma unroll
        for (int i = 0; i < 46; i++) tvv[i] = tile[(vq*86 + t0 + i)*64 + c];
        #pragma unroll
        for (int dt = 0; dt < 7; dt++){
            float wvv = W[OFF_W2L + (long)(c*7+dt)*64 + lane];
            #pragma unroll
            for (int k = 0; k < 40; k++) acc[k] += wvv * tvv[k+dt];
        }
    }
    __syncthreads();
    int row = wv*40;
    for (int k = 0; k < 40; k++) tile[(row+k)*64 + lane] = acc[k] + be2[lane];
    __syncthreads();
    for (int it = 0; it < 10; it++){
        int r = it*16 + (tid>>4), j = tid & 15;
        float a2 = fbbs[j];
        #pragma unroll 8
        for (int o = 0; o < 64; o++) a2 += fbws[j*65+o]*tile[r*64+o];
        a2 = a2 > 0.f ? a2 : 0.1f*a2;
        int vq2 = r/80, tt = r%80;
        W[OFF_Y + ((long)(b*80+tt)*200 + v0+vq2)*16 + j] = a2;
    }
}

// ---------------- sp linear 3200->64 ----------------
__global__ void __launch_bounds__(256) ksp(const float* __restrict__ sp_b, float* __restrict__ W)
{
    __shared__ float yb[3200];
    __shared__ float part[4][64];
    int bt = blockIdx.x, tid = threadIdx.x;
    int lane = tid & 63, wv = tid >> 6;
    for (int i = tid; i < 3200; i += 256) yb[i] = W[OFF_Y + (long)bt*3200 + i];
    __syncthreads();
    float acc = 0.f;
    int base = wv*800;
    for (int vj = 0; vj < 800; vj++)
        acc += W[OFF_SPWT + (long)(base+vj)*64 + lane] * yb[base+vj];
    part[wv][lane] = acc;
    __syncthreads();
    if (tid < 64){
        float s = part[0][tid]+part[1][tid]+part[2][tid]+part[3][tid] + sp_b[tid];
        W[OFF_XS0 + bt*64 + tid] = s;
    }
}

// ---------------- MHA + LN1 + FF + LN2 + mean(T) per batch ----------------
__global__ void __launch_bounds__(256) kattn(const float* __restrict__ inb, const float* __restrict__ ob,
    const float* __restrict__ l1g, const float* __restrict__ l1b,
    const float* __restrict__ l2g, const float* __restrict__ l2b,
    const float* __restrict__ f1b, const float* __restrict__ f2b,
    float* __restrict__ W)
{
    extern __shared__ float sm[];
    float* xb  = sm;          // 80*65
    float* qkv = sm + 5200;   // 80*193
    float* ao  = sm + 20640;  // 80*65
    float* pb  = sm + 25840;  // 4*80
    int b = blockIdx.x, tid = threadIdx.x, lane = tid & 63, wv = tid >> 6;
    for (int i = tid; i < 5120; i += 256){ int s = i>>6, c = i&63; xb[s*65+c] = W[OFF_XS0 + (b*80+s)*64 + c]; }
    __syncthreads();
    for (int s = wv; s < 80; s += 4){
        for (int ig = 0; ig < 3; ig++){
            int i = ig*64 + lane;
            float a = inb[i];
            #pragma unroll 8
            for (int c = 0; c < 64; c++) a += xb[s*65+c]*W[OFF_WINT + c*192 + i];
            qkv[s*193 + i] = a;
        }
    }
    __syncthreads();
    int h = wv;
    for (int i = 0; i < 80; i++){
        float qv[16];
        #pragma unroll
        for (int d = 0; d < 16; d++) qv[d] = qkv[i*193 + h*16 + d];
        float z[2];
        float m = -3.4e38f;
        #pragma unroll
        for (int u = 0; u < 2; u++){
            int jj = lane + u*64;
            z[u] = -3.4e38f;
            if (jj < 80){
                float a = 0.f;
                #pragma unroll
                for (int d = 0; d < 16; d++) a += qv[d]*qkv[jj*193 + 64 + h*16 + d];
                z[u] = a*0.25f;
                m = fmaxf(m, z[u]);
            }
        }
        m = wmax(m);
        float den = 0.f;
        #pragma unroll
        for (int u = 0; u < 2; u++){
            int jj = lane + u*64;
            if (jj < 80){
                float p = __expf(z[u]-m);
                pb[h*80+jj] = p;
                den += p;
            }
        }
        den = wsum(den);
        int d = lane & 15, jg = lane >> 4;
        float a = 0.f;
        for (int jo = 0; jo < 20; jo++){
            int jj = jg*20 + jo;
            a += pb[h*80+jj]*qkv[jj*193 + 128 + h*16 + d];
        }
        a += __shfl_xor(a, 16);
        a += __shfl_xor(a, 32);
        if (lane < 16) ao[i*65 + h*16 + lane] = a/den;
    }
    __syncthreads();
    for (int s = wv; s < 80; s += 4){
        float pr = ob[lane];
        #pragma unroll 8
        for (int e = 0; e < 64; e++) pr += ao[s*65+e]*W[OFF_OWT + e*64 + lane];
        float val = xb[s*65+lane] + pr;
        float mu = wsum(val)*(1.f/64.f);
        float dfv = val - mu;
        float var = wsum(dfv*dfv)*(1.f/64.f);
        xb[s*65+lane] = dfv*rsqrtf(var+1e-5f)*l1g[lane] + l1b[lane];
    }
    __syncthreads();
    for (int s = wv; s < 80; s += 4){
        for (int rg = 0; rg < 2; rg++){
            int r = rg*64+lane;
            float a = f1b[r];
            #pragma unroll 8
            for (int c = 0; c < 64; c++) a += xb[s*65+c]*W[OFF_F1T + c*128 + r];
            qkv[s*193 + r] = fmaxf(a, 0.f);
        }
    }
    __syncthreads();
    for (int s = wv; s < 80; s += 4){
        float a = f2b[lane];
        #pragma unroll 8
        for (int r = 0; r < 128; r++) a += qkv[s*193+r]*W[OFF_F2T + r*64 + lane];
        float val = xb[s*65+lane] + a;
        float mu = wsum(val)*(1.f/64.f);
        float dfv = val - mu;
        float var = wsum(dfv*dfv)*(1.f/64.f);
        xb[s*65+lane] = dfv*rsqrtf(var+1e-5f)*l2g[lane] + l2b[lane];
    }
    __syncthreads();
    if (tid < 64){
        float a = 0.f;
        for (int s = 0; s < 80; s++) a += xb[s*65+tid];
        W[OFF_FEATST + b*64 + tid] = a*(1.f/80.f);
    }
}

// ---------------- Gram: A = xc/sqrt(79), G = A A^T (5x5 register tiles, stride-204 LDS) ----------------
__global__ void __launch_bounds__(256) kgram(const float* __restrict__ x, float* __restrict__ W)
{
    extern __shared__ float sm[]; // xb[80*204] = 16320
    float* xb = sm;
    int b = blockIdx.x, tid = threadIdx.x;
    for (int i = tid; i < 16000; i += 256){ int t = i/200, n = i%200; xb[t*204+n] = x[b*16000 + i]; }
    __syncthreads();
    const float is79 = rsqrtf(79.f);
    if (tid < 200){
        int n = tid;
        float mu = 0.f;
        for (int t = 0; t < 80; t++) mu += xb[t*204+n];
        mu *= (1.f/80.f);
        for (int t = 0; t < 80; t++) xb[t*204+n] = (xb[t*204+n]-mu)*is79;
    }
    __syncthreads();
    for (int i = tid; i < 16000; i += 256){ int t = i/200, n = i%200; W[OFF_A + b*16000 + i] = xb[t*204+n]; }
    // G: 16x16 thread tiles of 5x5
    {
        int ti = (tid>>4)*5, tj = (tid&15)*5;
        const float4* X4 = (const float4*)xb;   // row stride 51 float4
        float acc[25];
        #pragma unroll
        for (int i = 0; i < 25; i++) acc[i] = 0.f;
        for (int n4 = 0; n4 < 50; n4++){
            float4 xi[5], xj[5];
            #pragma unroll
            for (int r = 0; r < 5; r++) xi[r] = X4[(ti+r)*51 + n4];
            #pragma unroll
            for (int c = 0; c < 5; c++) xj[c] = X4[(tj+c)*51 + n4];
            #pragma unroll
            for (int r = 0; r < 5; r++)
                #pragma unroll
                for (int c = 0; c < 5; c++)
                    acc[r*5+c] += xi[r].x*xj[c].x + xi[r].y*xj[c].y + xi[r].z*xj[c].z + xi[r].w*xj[c].w;
        }
        #pragma unroll
        for (int r = 0; r < 5; r++)
            #pragma unroll
            for (int c = 0; c < 5; c++)
                W[OFF_G + b*6400 + (ti+r)*80 + (tj+c)] = acc[r*5+c];
    }
}

// ---------------- Chebyshev: M = f(G)·A, 16-col chunks, 208 blocks, 3 LDS ops/j ----------------
__global__ void __launch_bounds__(256) kcheb(ChebC C, float* __restrict__ W)
{
    extern __shared__ float sm[];
    float* Gs = sm;          // 10240
    float* Tb = sm + 10240;  // 2x1280
    int blk = blockIdx.x, tid = threadIdx.x;
    int b = blk / 13, ch = blk % 13;
    int cl = tid & 15, rg = tid >> 4;
    int c = ch*16 + cl;
    bool act = (c < 200);
    for (int idx = tid; idx < 6400; idx += 256){
        int jj = idx / 80, ii = idx % 80;
        float v = W[OFF_G + b*6400 + jj*80 + ii] * C.alpha + ((ii==jj)? C.beta : 0.f);
        Gs[jj*128 + (ii/5)*8 + (ii%5)] = v;
    }
    const float* Ab = &W[OFF_A + (long)b*16000];
    float Tprev[5], Tcur[5], Macc[5];
    float* B0 = Tb; float* B1 = Tb + 1280;
    if (act){
        #pragma unroll
        for (int r = 0; r < 5; r++){
            int i = rg*5 + r;
            float v = Ab[i*200 + c];
            B0[i*16 + cl] = v;
            Tprev[r] = v;
            Macc[r] = C.c[0]*v;
        }
    }
    __syncthreads();
    const float* grow = Gs + rg*8;
    {
        float t[5] = {0.f,0.f,0.f,0.f,0.f};
        if (act){
            for (int j = 0; j < 80; j++){
                float bv = B0[j*16 + cl];
                const float4 g4 = *(const float4*)(grow + j*128);
                float g1 = grow[j*128 + 4];
                t[0] += g4.x*bv; t[1] += g4.y*bv; t[2] += g4.z*bv; t[3] += g4.w*bv; t[4] += g1*bv;
            }
            #pragma unroll
            for (int r = 0; r < 5; r++){
                Tcur[r] = t[r];
                Macc[r] += C.c[1]*t[r];
                B1[(rg*5+r)*16 + cl] = t[r];
            }
        }
        __syncthreads();
    }
    for (int k = 2; k < CHEB_N; k++){
        const float* Rb = Tb + ((k-1)&1)*1280;
        float* Wb = Tb + (k&1)*1280;
        if (act){
            float t[5] = {0.f,0.f,0.f,0.f,0.f};
            for (int j = 0; j < 80; j++){
                float bv = Rb[j*16 + cl];
                const float4 g4 = *(const float4*)(grow + j*128);
                float g1 = grow[j*128 + 4];
                t[0] += g4.x*bv; t[1] += g4.y*bv; t[2] += g4.z*bv; t[3] += g4.w*bv; t[4] += g1*bv;
            }
            float ck = C.c[k];
            #pragma unroll
            for (int r = 0; r < 5; r++){
                float tn = 2.f*t[r] - Tprev[r];
                Macc[r] += ck*tn;
                Tprev[r] = Tcur[r];
                Tcur[r] = tn;
                Wb[(rg*5+r)*16 + cl] = tn;
            }
        }
        __syncthreads();
    }
    if (act){
        #pragma unroll
        for (int r = 0; r < 5; r++)
            W[OFF_M + (long)b*16000 + (rg*5+r)*200 + c] = Macc[r];
    }
}

// ---------------- tv = upper-tri(A^T M + logc*I) ----------------
__global__ void ktv(float* __restrict__ W)
{
    __shared__ float an[80];
    int bid = blockIdx.x, tid = threadIdx.x;
    int b = bid/200, n = bid%200;
    for (int i = tid; i < 80; i += 64) an[i] = W[OFF_A + (long)b*16000 + i*200 + n];
    __syncthreads();
    long tb = OFF_TV + (long)b*20100 + (long)n*200 - (long)n*(n-1)/2;
    for (int m = n + tid; m < 200; m += 64){
        float a = 0.f;
        for (int i = 0; i < 80; i++) a += an[i]*W[OFF_M + (long)b*16000 + i*200 + m];
        if (m == n) a += LOGC;
        W[tb + (m-n)] = a;
    }
}

// ---------------- tn1 linear 20100->256 (block per output r, all batches) ----------------
__global__ void __launch_bounds__(256) ktn1(const float* __restrict__ w, const float* __restrict__ bias,
                                            float* __restrict__ W)
{
    __shared__ float part[4][16];
    int r = blockIdx.x, tid = threadIdx.x, lane = tid & 63, wv = tid >> 6;
    float acc[16];
    #pragma unroll
    for (int i = 0; i < 16; i++) acc[i] = 0.f;
    for (int vj = tid; vj < 20100; vj += 256){
        float wvv = w[(long)r*20100 + vj];
        #pragma unroll
        for (int bb = 0; bb < 16; bb++) acc[bb] += wvv * W[OFF_TV + (long)bb*20100 + vj];
    }
    #pragma unroll
    for (int bb = 0; bb < 16; bb++) acc[bb] = wsum(acc[bb]);
    if (lane == 0){
        #pragma unroll
        for (int bb = 0; bb < 16; bb++) part[wv][bb] = acc[bb];
    }
    __syncthreads();
    if (tid < 16){
        float s = part[0][tid]+part[1][tid]+part[2][tid]+part[3][tid] + bias[r];
        W[OFF_TN1O + tid*256 + r] = s;
    }
}

// ---------------- head: tn2 + concat + cls/site (one block per batch) ----------------
__global__ void __launch_bounds__(256) khead(const float* __restrict__ tn2w, const float* __restrict__ tn2b,
                      const float* __restrict__ cl1w, const float* __restrict__ cl1b,
                      const float* __restrict__ cl2w, const float* __restrict__ cl2b,
                      const float* __restrict__ sc1w, const float* __restrict__ sc1b,
                      const float* __restrict__ sc2w, const float* __restrict__ sc2b,
                      const float* __restrict__ W, float* __restrict__ out)
{
    __shared__ float g[256], feats[128], h1[64], h2[32];
    int b = blockIdx.x, tid = threadIdx.x;
    float v = W[OFF_TN1O + b*256 + tid] * BN_SC;
    g[tid] = v > 0.f ? v : 0.1f*v;
    if (tid < 64) feats[tid] = W[OFF_FEATST + b*64 + tid];
    __syncthreads();
    {
        int o = tid >> 2, s3 = tid & 3;
        const float* wrow = tn2w + o*256 + s3*64;
        const float* grow = g + s3*64;
        float acc = 0.f;
        #pragma unroll 8
        for (int e = 0; e < 64; e++) acc += wrow[e]*grow[e];
        acc += __shfl_xor(acc, 1);
        acc += __shfl_xor(acc, 2);
        if (s3 == 0) feats[64+o] = fmaxf(acc + tn2b[o], 0.f);
    }
    __syncthreads();
    if (tid < 64){
        float a = cl1b[tid];
        #pragma unroll 8
        for (int k = 0; k < 128; k++) a += cl1w[tid*128+k]*feats[k];
        h1[tid] = fmaxf(a, 0.f);
    } else if (tid < 96){
        int i = tid-64;
        float a = sc1b[i];
        #pragma unroll 8
        for (int k = 0; k < 128; k++) a += sc1w[i*128+k]*feats[k];
        h2[i] = fmaxf(a, 0.f);
    }
    __syncthreads();
    if (tid < 2){
        float a = cl2b[tid];
        for (int i = 0; i < 64; i++) a += cl2w[tid*64+i]*h1[i];
        out[b*2+tid] = a;
    } else if (tid >= 32 && tid < 49){
        int o = tid-32;
        float a = sc2b[o];
        for (int i = 0; i < 32; i++) a += sc2w[o*32+i]*h2[i];
        out[32 + b*17 + o] = a;
    }
}

extern "C" void kernel_launch(void* const* d_in, const int* in_sizes, int n_in,
                              void* d_out, int out_size, void* d_ws, size_t ws_size,
                              hipStream_t stream)
{
    const float* x     = (const float*)d_in[0];
    const float* adj   = (const float*)d_in[1];
    const float* g1W   = (const float*)d_in[2];
    const float* g1a   = (const float*)d_in[3];
    const float* b1c3w = (const float*)d_in[4];
    const float* b1c3b = (const float*)d_in[5];
    const float* b1c5w = (const float*)d_in[6];
    const float* b1c5b = (const float*)d_in[7];
    const float* b1c7w = (const float*)d_in[8];
    const float* b1c7b = (const float*)d_in[9];
    const float* b1fw  = (const float*)d_in[10];
    const float* b1fb  = (const float*)d_in[11];
    const float* g2W   = (const float*)d_in[12];
    const float* g2a   = (const float*)d_in[13];
    const float* b2c3w = (const float*)d_in[14];
    const float* b2c3b = (const float*)d_in[15];
    const float* b2c5w = (const float*)d_in[16];
    const float* b2c5b = (const float*)d_in[17];
    const float* b2c7w = (const float*)d_in[18];
    const float* b2c7b = (const float*)d_in[19];
    const float* b2fw  = (const float*)d_in[20];
    const float* b2fb  = (const float*)d_in[21];
    const float* fbw   = (const float*)d_in[22];
    const float* fbb   = (const float*)d_in[23];
    const float* spw   = (const float*)d_in[24];
    const float* spb   = (const float*)d_in[25];
    const float* ainw  = (const float*)d_in[26];
    const float* ainb  = (const float*)d_in[27];
    const float* aow   = (const float*)d_in[28];
    const float* aob   = (const float*)d_in[29];
    const float* ln1g  = (const float*)d_in[30];
    const float* ln1b  = (const float*)d_in[31];
    const float* ln2g  = (const float*)d_in[32];
    const float* ln2b  = (const float*)d_in[33];
    const float* ff1w  = (const float*)d_in[34];
    const float* ff1b  = (const float*)d_in[35];
    const float* ff2w  = (const float*)d_in[36];
    const float* ff2b  = (const float*)d_in[37];
    const float* tn1w  = (const float*)d_in[38];
    const float* tn1b  = (const float*)d_in[39];
    const float* tn2w  = (const float*)d_in[40];
    const float* tn2b  = (const float*)d_in[41];
    const float* cl1w  = (const float*)d_in[42];
    const float* cl1b  = (const float*)d_in[43];
    const float* cl2w  = (const float*)d_in[44];
    const float* cl2b  = (const float*)d_in[45];
    const float* sc1w  = (const float*)d_in[46];
    const float* sc1b  = (const float*)d_in[47];
    const float* sc2w  = (const float*)d_in[48];
    const float* sc2b  = (const float*)d_in[49];
    float* W = (float*)d_ws;
    float* out = (float*)d_out;

    // Chebyshev coefficients of f(x)=log1p(x*1e4)/x on [0.10, 9.0] (host, deterministic)
    ChebC ch;
    {
        const double aa = 0.10, bb = 9.0;
        const int NK = 128;
        const double PI = 3.14159265358979323846;
        for (int k = 0; k < CHEB_N; k++){
            double s = 0.0;
            for (int j = 0; j < NK; j++){
                double th = PI*(j+0.5)/NK;
                double xx = 0.5*(bb+aa) + 0.5*(bb-aa)*cos(th);
                double f = log1p(xx*1e4)/xx;
                s += f*cos(k*th);
            }
            double ck = 2.0*s/NK;
            ch.c[k] = (float)(k==0 ? 0.5*ck : ck);
        }
        ch.alpha = (float)(2.0/(bb-aa));
        ch.beta  = (float)(-(bb+aa)/(bb-aa));
    }

    kprep<<<163, 256, 0, stream>>>(spw, b2fw, b2c3w, b2c5w, b2c7w, b2c3b, b2c5b, b2c7b, b2fb,
                                   g1W, g1a, b1c3w, b1c5w, b1c7w, b1c3b, b1c5b, b1c7b, b1fw, b1fb,
                                   adj, g2W, ainw, aow, ff1w, ff2w, W);
    kgat1<<<1280, 256, 0, stream>>>(x, W);
    kgat2<<<1280, 256, 70752, stream>>>(g2a, W);
    kconv2fb<<<1600, 256, 48512, stream>>>(fbw, fbb, W);
    ksp<<<1280, 256, 0, stream>>>(spb, W);
    kattn<<<16, 256, 104640, stream>>>(ainb, aob, ln1g, ln1b, ln2g, ln2b, ff1b, ff2b, W);
    kgram<<<16, 256, 65280, stream>>>(x, W);
    kcheb<<<208, 256, 51200, stream>>>(ch, W);
    ktv<<<3200, 64, 0, stream>>>(W);
    ktn1<<<256, 256, 0, stream>>>(tn1w, tn1b, W);
    khead<<<16, 256, 0, stream>>>(tn2w, tn2b, cl1w, cl1b, cl2w, cl2b, sc1w, sc1b, sc2w, sc2b, W, out);
}